// Round 3
// baseline (2966.702 us; speedup 1.0000x reference)
//
#include <hip/hip_runtime.h>
#include <hip/hip_bf16.h>

#define N_ATOMS 10000
#define N_PAIRS 320000
#define C_ 64
#define NB_ 10

__device__ __forceinline__ float bf2f(__hip_bfloat16 x) { return __bfloat162float(x); }
// dtype-agnostic load: isf32 is wave-uniform
__device__ __forceinline__ float ldf(const void* p, int i, int isf32) {
    return isf32 ? ((const float*)p)[i] : bf2f(((const __hip_bfloat16*)p)[i]);
}

// weight buffer offsets (float elements) inside wbuf
#define W_PPREW1 0
#define W_PPREB1 4096
#define W_PPREW2 4160
#define W_PPREB2 8256
#define W_PIW    8320
#define W_PIB    90240
#define W_IIW    90880
#define W_PPOSTW1 99072
#define W_PPOSTW2 107264
#define W_EQW    111360
#define W_Q1W    115456
#define W_Q1B    123648
#define W_Q2W    123712
#define W_Q2B    131904
#define W_TOTAL  132032

// ---------------- Probe: decide f32 vs bf16 by unit-norm test on d3 ----------------
__global__ void k_probe(const void* __restrict__ d3, int* __restrict__ flag)
{
    if (threadIdx.x == 0 && blockIdx.x == 0) {
        float sf = 0.f, sb = 0.f;
        const float* f = (const float*)d3;
        const __hip_bfloat16* b = (const __hip_bfloat16*)d3;
        for (int r = 0; r < 4; r++) {
            float x = f[r * 3], y = f[r * 3 + 1], z = f[r * 3 + 2];
            float n = x * x + y * y + z * z;
            sf += isfinite(n) ? fabsf(n - 1.f) : 1e30f;
            float xb = bf2f(b[r * 3]), yb = bf2f(b[r * 3 + 1]), zb = bf2f(b[r * 3 + 2]);
            float nb = xb * xb + yb * yb + zb * zb;
            sb += isfinite(nb) ? fabsf(nb - 1.f) : 1e30f;
        }
        *flag = (sf < sb) ? 1 : 0;
    }
}

// ---------------- Convert all weights/biases into f32 wbuf (lossless) ----------------
__global__ __launch_bounds__(256) void k_convert(
    const void* s0, const void* s1, const void* s2, const void* s3,
    const void* s4, const void* s5, const void* s6, const void* s7,
    const void* s8, const void* s9, const void* s10, const void* s11,
    const void* s12, const void* s13,
    float* __restrict__ wbuf, const int* __restrict__ flagp)
{
    const int idx = blockIdx.x * 256 + threadIdx.x;
    if (idx >= W_TOTAL) return;
    const int isf32 = *flagp;
    const int offs[15] = {W_PPREW1, W_PPREB1, W_PPREW2, W_PPREB2, W_PIW, W_PIB,
                          W_IIW, W_PPOSTW1, W_PPOSTW2, W_EQW, W_Q1W, W_Q1B,
                          W_Q2W, W_Q2B, W_TOTAL};
    const void* srcs[14] = {s0, s1, s2, s3, s4, s5, s6, s7, s8, s9, s10, s11, s12, s13};
    int t = 0;
    while (idx >= offs[t + 1]) t++;
    wbuf[idx] = ldf(srcs[t], idx - offs[t], isf32);
}

// ---------------- Kernel 1: p1_in = tanh(tanh(p1@W1+b1)@W2+b2) ----------------
__global__ __launch_bounds__(256) void k_p1in(
    const void* __restrict__ p1,
    const float* __restrict__ wbuf,
    const int* __restrict__ flagp,
    float* __restrict__ p1_in)
{
    const float* W1 = wbuf + W_PPREW1;
    const float* b1 = wbuf + W_PPREB1;
    const float* W2 = wbuf + W_PPREW2;
    const float* b2 = wbuf + W_PPREB2;
    const int isf32 = *flagp;
    __shared__ float x[4][C_];
    __shared__ float h[4][C_];
    const int t = threadIdx.x;
    const int slot = t >> 6;
    const int c = t & 63;
    const int atom = blockIdx.x * 4 + slot;
    x[slot][c] = ldf(p1, atom * C_ + c, isf32);
    __syncthreads();
    float acc = b1[c];
    for (int k = 0; k < C_; k++) acc += x[slot][k] * W1[k * C_ + c];
    h[slot][c] = tanhf(acc);
    __syncthreads();
    acc = b2[c];
    for (int k = 0; k < C_; k++) acc += h[slot][k] * W2[k * C_ + c];
    p1_in[atom * C_ + c] = tanhf(acc);
}

// ---------------- Kernel 2: v = segment_sum(d3 * fc_edge, i) ----------------
__global__ __launch_bounds__(256) void k_vscat(
    const int* __restrict__ ind2, const void* __restrict__ d3,
    const void* __restrict__ fc, const int* __restrict__ flagp,
    float* __restrict__ v)
{
    const int p = blockIdx.x * 256 + threadIdx.x;
    if (p >= N_PAIRS) return;
    const int isf32 = *flagp;
    const int ia = ind2[2 * p];
    const float f = ldf(fc, p, isf32);
    atomicAdd(&v[ia * 3 + 0], ldf(d3, p * 3 + 0, isf32) * f);
    atomicAdd(&v[ia * 3 + 1], ldf(d3, p * 3 + 1, isf32) * f);
    atomicAdd(&v[ia * 3 + 2], ldf(d3, p * 3 + 2, isf32) * f);
}

// ---------------- Kernel 3: main per-pair kernel ----------------
__global__ __launch_bounds__(256) void k_pairs(
    const int* __restrict__ ind2,
    const void* __restrict__ basis,
    const void* __restrict__ d3,
    const void* __restrict__ fc,
    const void* __restrict__ p3,
    const float* __restrict__ wbuf,
    const int* __restrict__ flagp,
    const float* __restrict__ p1_in,
    const float* __restrict__ vglob,
    float* __restrict__ p1scat,
    float* __restrict__ p3acc)
{
    const float* piW = wbuf + W_PIW;
    const float* piB = wbuf + W_PIB;
    const float* iiW = wbuf + W_IIW;

    __shared__ __align__(16) float pairX[16][128];
    __shared__ __align__(16) float preL[16][64];
    __shared__ float i1bL[16][64];
    __shared__ float basisL[16][NB_];
    __shared__ float d3L[16][3];
    __shared__ float t3L[16][3];
    __shared__ float fcL[16];
    __shared__ float tbL[16];
    __shared__ int sI[16], sJ[16];

    const int t = threadIdx.x;
    const int pb = blockIdx.x * 16;
    const int isf32 = *flagp;

    // ---- phase 0: stage indices / basis / d3 / fc ----
    if (t < 16) {
        sI[t] = ind2[(pb + t) * 2];
        sJ[t] = ind2[(pb + t) * 2 + 1];
        fcL[t] = ldf(fc, pb + t, isf32);
    } else if (t < 176) {
        const int q = t - 16;                   // 160 basis elements
        basisL[q / NB_][q % NB_] = ldf(basis, pb * NB_ + q, isf32);
    } else if (t < 224) {
        const int q = t - 176;                  // 48 d3 elements
        d3L[q / 3][q % 3] = ldf(d3, pb * 3 + q, isf32);
    }
    __syncthreads();

    // stage pair features [p1_in[i] | p1_in[j]]  (p1_in is our f32 ws buffer)
    for (int r = 0; r < 8; r++) {
        const int idx = t + 256 * r;            // 2048 elements
        const int p = idx >> 7;
        const int k = idx & 127;
        const int atom = (k < 64) ? sI[p] : sJ[p];
        pairX[p][k] = p1_in[atom * C_ + (k & 63)];
    }
    __syncthreads();

    const int q = t >> 6;   // pair group (4 pairs each)
    const int c = t & 63;   // channel

    // ---- phase A: h = tanh(pair@piW + b), pre = sum_b h*basis ----
    {
        float acc[4][10];
        #pragma unroll
        for (int pp = 0; pp < 4; pp++)
            #pragma unroll
            for (int b = 0; b < 10; b++) acc[pp][b] = 0.f;

        const float* wrow = piW + c * 10;       // 10 cols for this c
        for (int k4 = 0; k4 < 32; k4++) {
            float4 xx[4];
            #pragma unroll
            for (int pp = 0; pp < 4; pp++)
                xx[pp] = *(const float4*)&pairX[q * 4 + pp][k4 * 4];
            #pragma unroll
            for (int kk = 0; kk < 4; kk++) {
                const float2* wp = (const float2*)(wrow + (size_t)(k4 * 4 + kk) * 640);
                float2 u[5];
                #pragma unroll
                for (int b2 = 0; b2 < 5; b2++) u[b2] = wp[b2];
                #pragma unroll
                for (int pp = 0; pp < 4; pp++) {
                    const float xv = ((const float*)&xx[pp])[kk];
                    #pragma unroll
                    for (int b2 = 0; b2 < 5; b2++) {
                        acc[pp][2 * b2]     += xv * u[b2].x;
                        acc[pp][2 * b2 + 1] += xv * u[b2].y;
                    }
                }
            }
        }
        #pragma unroll
        for (int pp = 0; pp < 4; pp++) {
            const int p = q * 4 + pp;
            float pre = 0.f;
            #pragma unroll
            for (int b = 0; b < 10; b++)
                pre += tanhf(acc[pp][b] + piB[c * 10 + b]) * basisL[p][b];
            preL[p][c] = pre;
        }
    }
    __syncthreads();

    // ---- phase B: ip = tanh(pre @ iiW); scatter to p1scat; keep i1b ----
    {
        const int o0 = 2 * c;
        float acc2[4][2];
        #pragma unroll
        for (int pp = 0; pp < 4; pp++) { acc2[pp][0] = 0.f; acc2[pp][1] = 0.f; }
        const float* w2 = iiW + o0;             // cols 2c,2c+1; row stride 128
        for (int k4 = 0; k4 < 16; k4++) {
            float4 xx[4];
            #pragma unroll
            for (int pp = 0; pp < 4; pp++)
                xx[pp] = *(const float4*)&preL[q * 4 + pp][k4 * 4];
            #pragma unroll
            for (int kk = 0; kk < 4; kk++) {
                const float2 u = *(const float2*)(w2 + (size_t)(k4 * 4 + kk) * 128);
                #pragma unroll
                for (int pp = 0; pp < 4; pp++) {
                    const float xv = ((const float*)&xx[pp])[kk];
                    acc2[pp][0] += xv * u.x;
                    acc2[pp][1] += xv * u.y;
                }
            }
        }
        #pragma unroll
        for (int pp = 0; pp < 4; pp++) {
            const int p = q * 4 + pp;
            const float v0 = tanhf(acc2[pp][0]);
            const float v1 = tanhf(acc2[pp][1]);
            atomicAdd(&p1scat[sI[p] * 128 + o0], v0);
            atomicAdd(&p1scat[sI[p] * 128 + o0 + 1], v1);
            if (o0 >= 64) { i1bL[p][o0 - 64] = v0; i1bL[p][o0 - 63] = v1; }
        }
    }

    // ---- geometry per pair (threads 0..15) ----
    if (t < 16) {
        const float vi0 = vglob[sI[t] * 3 + 0];
        const float vi1 = vglob[sI[t] * 3 + 1];
        const float vi2 = vglob[sI[t] * 3 + 2];
        const float d0 = d3L[t][0], d1 = d3L[t][1], d2 = d3L[t][2];
        const float proj = vi0 * d0 + vi1 * d1 + vi2 * d2;
        const float w0 = vi0 - proj * d0;
        const float w1 = vi1 - proj * d1;
        const float w2v = vi2 - proj * d2;
        const float w2 = w0 * w0 + w1 * w1 + w2v * w2v;
        const float g_deg = w2 / (w2 + 1e-4f);        // (10*EPS)^2
        const float rs = rsqrtf(w2 + 1e-6f);          // EPS^2
        t3L[t][0] = w0 * rs * g_deg;
        t3L[t][1] = w1 * rs * g_deg;
        t3L[t][2] = w2v * rs * g_deg;
        const float f = fcL[t];
        tbL[t] = g_deg * f * f;
    }
    __syncthreads();

    // ---- scatter ix -> p3acc ----
    #pragma unroll
    for (int pp = 0; pp < 4; pp++) {
        const int p = q * 4 + pp;
        const int ia = sI[p], ja = sJ[p];
        const float bv = i1bL[p][c];
        const float coef = bv * tbL[p];
        #pragma unroll
        for (int x = 0; x < 3; x++) {
            const float p3v = ldf(p3, ja * 192 + x * 64 + c, isf32);
            const float ixv = p3v * bv + d3L[p][x] * bv + t3L[p][x] * coef;
            atomicAdd(&p3acc[ia * 192 + x * 64 + c], ixv);
        }
    }
}

// ---------------- Kernel 4: per-atom epilogue ----------------
__global__ __launch_bounds__(256) void k_final(
    const float* __restrict__ p1scat, const float* __restrict__ p3acc,
    const float* __restrict__ wbuf, const int* __restrict__ flagp,
    void* __restrict__ out)
{
    const float* ppW1 = wbuf + W_PPOSTW1;
    const float* ppW2 = wbuf + W_PPOSTW2;
    const float* eqW  = wbuf + W_EQW;
    const float* q1W  = wbuf + W_Q1W;
    const float* q1b  = wbuf + W_Q1B;
    const float* q2W  = wbuf + W_Q2W;
    const float* q2b  = wbuf + W_Q2B;
    const int isf32 = *flagp;

    __shared__ float s1[4][128];
    __shared__ float hA[4][64];
    __shared__ float cat[4][128];
    __shared__ float p3a[4][192];
    const int t = threadIdx.x;
    const int slot = t >> 6;
    const int c = t & 63;
    const int atom = blockIdx.x * 4 + slot;

    s1[slot][c]        = p1scat[atom * 128 + c];
    s1[slot][64 + c]   = p1scat[atom * 128 + 64 + c];
    p3a[slot][c]       = p3acc[atom * 192 + c];
    p3a[slot][64 + c]  = p3acc[atom * 192 + 64 + c];
    p3a[slot][128 + c] = p3acc[atom * 192 + 128 + c];
    __syncthreads();

    // p1_new = tanh(tanh(p1_scat @ ppW1) @ ppW2)
    float acc = 0.f;
    for (int k = 0; k < 128; k++) acc += s1[slot][k] * ppW1[k * 64 + c];
    hA[slot][c] = tanhf(acc);
    __syncthreads();
    acc = 0.f;
    for (int k = 0; k < 64; k++) acc += hA[slot][k] * ppW2[k * 64 + c];
    cat[slot][c] = tanhf(acc);   // p1_new

    // p3_new = p3_acc @ eqW ; dotted = sum_x p3_new^2
    float pn[3];
    float dot = 0.f;
    #pragma unroll
    for (int x = 0; x < 3; x++) {
        float a = 0.f;
        for (int k = 0; k < 64; k++) a += p3a[slot][x * 64 + k] * eqW[k * 64 + c];
        pn[x] = a;
        dot += a * a;
    }
    cat[slot][64 + c] = dot;
    __syncthreads();

    // h2 = tanh(cat @ q1W + q1b)
    acc = q1b[c];
    for (int k = 0; k < 128; k++) acc += cat[slot][k] * q1W[k * 64 + c];
    __syncthreads();
    hA[slot][c] = tanhf(acc);
    __syncthreads();

    // h2b = tanh(h2 @ q2W + q2b); g1 = cols 0..63, g3 = cols 64..127
    float g1acc = q2b[c];
    float g3acc = q2b[c + 64];
    for (int k = 0; k < 64; k++) {
        const float hv = hA[slot][k];
        g1acc += hv * q2W[k * 128 + c];
        g3acc += hv * q2W[k * 128 + c + 64];
    }
    const float g1 = tanhf(g1acc);
    const float g3 = tanhf(g3acc);
    if (isf32) {
        float* p1_out = (float*)out;
        float* p3_out = p1_out + 640000;
        p1_out[atom * 64 + c] = g1;
        #pragma unroll
        for (int x = 0; x < 3; x++)
            p3_out[atom * 192 + x * 64 + c] = pn[x] * g3;
    } else {
        __hip_bfloat16* p1_out = (__hip_bfloat16*)out;
        __hip_bfloat16* p3_out = p1_out + 640000;
        p1_out[atom * 64 + c] = __float2bfloat16(g1);
        #pragma unroll
        for (int x = 0; x < 3; x++)
            p3_out[atom * 192 + x * 64 + c] = __float2bfloat16(pn[x] * g3);
    }
}

extern "C" void kernel_launch(void* const* d_in, const int* in_sizes, int n_in,
                              void* d_out, int out_size, void* d_ws, size_t ws_size,
                              hipStream_t stream)
{
    const int* ind2 = (const int*)d_in[0];
    const void* p1    = d_in[1];
    const void* p3    = d_in[2];
    const void* basis = d_in[3];
    const void* d3    = d_in[4];
    const void* fc    = d_in[5];

    float* ws = (float*)d_ws;
    float* v      = ws;                         // 30,000
    float* p1scat = v + 30000;                  // 1,280,000
    float* p3acc  = p1scat + 1280000;           // 1,920,000
    float* p1in   = p3acc + 1920000;            // 640,000
    float* wbuf   = p1in + 640000;              // 132,032 floats
    int* flag = (int*)(wbuf + W_TOTAL);

    hipMemsetAsync(ws, 0, (size_t)(30000 + 1280000 + 1920000) * sizeof(float), stream);

    k_probe<<<1, 64, 0, stream>>>(d3, flag);
    k_convert<<<(W_TOTAL + 255) / 256, 256, 0, stream>>>(
        d_in[6], d_in[7], d_in[8], d_in[9], d_in[10], d_in[11], d_in[12],
        d_in[13], d_in[14], d_in[15], d_in[16], d_in[17], d_in[18], d_in[19],
        wbuf, flag);

    k_p1in<<<2500, 256, 0, stream>>>(p1, wbuf, flag, p1in);
    k_vscat<<<1250, 256, 0, stream>>>(ind2, d3, fc, flag, v);
    k_pairs<<<20000, 256, 0, stream>>>(ind2, basis, d3, fc, p3, wbuf, flag,
                                       p1in, v, p1scat, p3acc);
    k_final<<<2500, 256, 0, stream>>>(p1scat, p3acc, wbuf, flag, d_out);
}

// Round 5
// 687.886 us; speedup vs baseline: 4.3128x; 4.3128x over previous
//
#include <hip/hip_runtime.h>
#include <hip/hip_bf16.h>

#define N_ATOMS 10000
#define N_PAIRS 320000
#define C_ 64
#define NB_ 10

typedef short bf16x8 __attribute__((ext_vector_type(8)));
typedef float f32x4 __attribute__((ext_vector_type(4)));

__device__ __forceinline__ float bf2f(__hip_bfloat16 x) { return __bfloat162float(x); }
__device__ __forceinline__ float ldf(const void* p, int i, int isf32) {
    return isf32 ? ((const float*)p)[i] : bf2f(((const __hip_bfloat16*)p)[i]);
}
__device__ __forceinline__ short f2bs(float x) {
    __hip_bfloat16 h = __float2bfloat16(x);
    return *reinterpret_cast<short*>(&h);
}
__device__ __forceinline__ float bs2f(short s) {
    return __uint_as_float(((unsigned)(unsigned short)s) << 16);
}

// wbuf f32 offsets
#define W_PPREW1 0
#define W_PPREB1 4096
#define W_PPREW2 4160
#define W_PPREB2 8256
#define W_PIW    8320
#define W_PIB    90240
#define W_IIW    90880
#define W_PPOSTW1 99072
#define W_PPOSTW2 107264
#define W_EQW    111360
#define W_Q1W    115456
#define W_Q1B    123648
#define W_Q2W    123712
#define W_Q2B    131904
#define W_TOTAL  132032

// ---------------- probe dtype ----------------
__global__ void k_probe(const void* __restrict__ d3, int* __restrict__ flag)
{
    if (threadIdx.x == 0 && blockIdx.x == 0) {
        float sf = 0.f, sb = 0.f;
        const float* f = (const float*)d3;
        const __hip_bfloat16* b = (const __hip_bfloat16*)d3;
        for (int r = 0; r < 4; r++) {
            float x = f[r*3], y = f[r*3+1], z = f[r*3+2];
            float n = x*x + y*y + z*z;
            sf += isfinite(n) ? fabsf(n - 1.f) : 1e30f;
            float xb = bf2f(b[r*3]), yb = bf2f(b[r*3+1]), zb = bf2f(b[r*3+2]);
            float nb = xb*xb + yb*yb + zb*zb;
            sb += isfinite(nb) ? fabsf(nb - 1.f) : 1e30f;
        }
        *flag = (sf < sb) ? 1 : 0;
    }
}

// ---------------- gather all weights into f32 wbuf ----------------
__global__ __launch_bounds__(256) void k_convert(
    const void* s0, const void* s1, const void* s2, const void* s3,
    const void* s4, const void* s5, const void* s6, const void* s7,
    const void* s8, const void* s9, const void* s10, const void* s11,
    const void* s12, const void* s13,
    float* __restrict__ wbuf, const int* __restrict__ flagp)
{
    const int idx = blockIdx.x * 256 + threadIdx.x;
    if (idx >= W_TOTAL) return;
    const int isf32 = *flagp;
    const int offs[15] = {W_PPREW1, W_PPREB1, W_PPREW2, W_PPREB2, W_PIW, W_PIB,
                          W_IIW, W_PPOSTW1, W_PPOSTW2, W_EQW, W_Q1W, W_Q1B,
                          W_Q2W, W_Q2B, W_TOTAL};
    const void* srcs[14] = {s0,s1,s2,s3,s4,s5,s6,s7,s8,s9,s10,s11,s12,s13};
    int t = 0;
    while (idx >= offs[t + 1]) t++;
    wbuf[idx] = ldf(srcs[t], idx - offs[t], isf32);
}

// ---------------- pack MFMA B-operand buffers (hi + lo split) ----------------
// piWB{h,l}[((T*4+s)*64 + lane)*8 + j] = piW[k][colnat],
//   k = s*32 + (lane>>4)*8 + j, col' = T*16 + (lane&15), b=col'>>6, c=col'&63,
//   colnat = c*10 + b
// iiW{h,l}[((ct*2+s2)*64+lane)*8+j]: k = s2*32+(lane>>4)*8+j, col = ct*16+(lane&15)
__global__ __launch_bounds__(256) void k_pack(
    const float* __restrict__ wbuf,
    short* __restrict__ piWBh, short* __restrict__ piWBl,
    short* __restrict__ iiWh, short* __restrict__ iiWl)
{
    int idx = blockIdx.x * 256 + threadIdx.x;
    if (idx < 81920) {
        const int j = idx & 7, lane = (idx >> 3) & 63, s = (idx >> 9) & 3, T = idx >> 11;
        const int k = s * 32 + (lane >> 4) * 8 + j;
        const int colp = T * 16 + (lane & 15);
        const int b = colp >> 6, c = colp & 63;
        const float v = wbuf[W_PIW + k * 640 + c * 10 + b];
        const short hs = f2bs(v);
        piWBh[idx] = hs;
        piWBl[idx] = f2bs(v - bs2f(hs));
        return;
    }
    idx -= 81920;
    if (idx < 8192) {   // FIX: iiW has 8192 elements (was 16384 -> buffer overflow race)
        const int j = idx & 7, lane = (idx >> 3) & 63, s2 = (idx >> 9) & 1, ct = idx >> 10;
        const int k = s2 * 32 + (lane >> 4) * 8 + j;
        const int col = ct * 16 + (lane & 15);
        const float wv = wbuf[W_IIW + k * 128 + col];
        const short hs = f2bs(wv);
        iiWh[idx] = hs;
        iiWl[idx] = f2bs(wv - bs2f(hs));
    }
}

// ---------------- p1_in split into hi/lo bf16 ----------------
__global__ __launch_bounds__(256) void k_p1in(
    const void* __restrict__ p1, const float* __restrict__ wbuf,
    const int* __restrict__ flagp,
    unsigned short* __restrict__ p1h, unsigned short* __restrict__ p1l)
{
    const float* W1 = wbuf + W_PPREW1;
    const float* b1 = wbuf + W_PPREB1;
    const float* W2 = wbuf + W_PPREW2;
    const float* b2 = wbuf + W_PPREB2;
    const int isf32 = *flagp;
    __shared__ float x[4][C_];
    __shared__ float h[4][C_];
    const int t = threadIdx.x;
    const int slot = t >> 6, c = t & 63;
    const int atom = blockIdx.x * 4 + slot;
    x[slot][c] = ldf(p1, atom * C_ + c, isf32);
    __syncthreads();
    float acc = b1[c];
    for (int k = 0; k < C_; k++) acc += x[slot][k] * W1[k * C_ + c];
    h[slot][c] = tanhf(acc);
    __syncthreads();
    acc = b2[c];
    for (int k = 0; k < C_; k++) acc += h[slot][k] * W2[k * C_ + c];
    const float f = tanhf(acc);
    const short hs = f2bs(f);
    p1h[atom * C_ + c] = (unsigned short)hs;
    p1l[atom * C_ + c] = (unsigned short)f2bs(f - bs2f(hs));
}

// ---------------- sort machinery (full path) ----------------
__global__ __launch_bounds__(256) void k_hist(const int* __restrict__ ind2, int* __restrict__ cnt)
{
    const int p = blockIdx.x * 256 + threadIdx.x;
    if (p < N_PAIRS) atomicAdd(&cnt[ind2[2 * p]], 1);
}
__global__ __launch_bounds__(256) void k_scan(const int* __restrict__ cnt, int* __restrict__ offs)
{
    __shared__ int part[256];
    __shared__ int base[257];
    const int t = threadIdx.x;
    const int lo = t * 40, hi = (lo + 40 < N_ATOMS) ? lo + 40 : N_ATOMS;
    int s = 0;
    for (int b = lo; b < hi; b++) s += cnt[b];
    part[t] = s;
    __syncthreads();
    if (t == 0) {
        int run = 0;
        for (int i = 0; i < 256; i++) { base[i] = run; run += part[i]; }
        base[256] = run;
    }
    __syncthreads();
    int run = base[t];
    for (int b = lo; b < hi; b++) { offs[b] = run; run += cnt[b]; }
    if (t == 0) offs[N_ATOMS] = base[256];
}
__global__ __launch_bounds__(256) void k_cpcur(const int* __restrict__ offs, int* __restrict__ cur)
{
    const int i = blockIdx.x * 256 + threadIdx.x;
    if (i < N_ATOMS) cur[i] = offs[i];
}
__global__ __launch_bounds__(256) void k_scatter(const int* __restrict__ ind2,
                                                 int* __restrict__ cur, int* __restrict__ perm)
{
    const int p = blockIdx.x * 256 + threadIdx.x;
    if (p >= N_PAIRS) return;
    const int pos = atomicAdd(&cur[ind2[2 * p]], 1);
    perm[pos] = p;
}

// ---------------- v scatter (atomic path only) ----------------
__global__ __launch_bounds__(256) void k_vscat(
    const int* __restrict__ ind2, const void* __restrict__ d3,
    const void* __restrict__ fc, const int* __restrict__ flagp, float* __restrict__ v)
{
    const int p = blockIdx.x * 256 + threadIdx.x;
    if (p >= N_PAIRS) return;
    const int isf32 = *flagp;
    const int ia = ind2[2 * p];
    const float f = ldf(fc, p, isf32);
    atomicAdd(&v[ia * 3 + 0], ldf(d3, p * 3 + 0, isf32) * f);
    atomicAdd(&v[ia * 3 + 1], ldf(d3, p * 3 + 1, isf32) * f);
    atomicAdd(&v[ia * 3 + 2], ldf(d3, p * 3 + 2, isf32) * f);
}

// ---------------- main per-pair MFMA kernel (split-bf16 GEMMs) ----------------
template<int FULLMODE>
__global__ __launch_bounds__(256) void k_pairs_t(
    const int* __restrict__ ind2, const void* __restrict__ basis,
    const void* __restrict__ d3, const void* __restrict__ fc,
    const void* __restrict__ p3,
    const float* __restrict__ wbuf,
    const short* __restrict__ piWBh, const short* __restrict__ piWBl,
    const short* __restrict__ iiWh, const short* __restrict__ iiWl,
    const unsigned short* __restrict__ p1h, const unsigned short* __restrict__ p1l,
    const int* __restrict__ flagp, const float* __restrict__ vglob,
    float* __restrict__ outA, float* __restrict__ outB)
{
    // SH (32 KB) reused three ways with barriers at each transition:
    //   phase 1: X staging  (Xh @0 16K, Xl @16K 16K)
    //   phase 2: preL @0 (17408 B)
    //   phase 3: i1bL @16K (16 KB, FULLMODE=0 only)
    __shared__ __align__(16) char SH[32768];
    __shared__ __align__(16) unsigned short Bbuf[8192];   // 16 KB B-chunk
    __shared__ float basisL[640];
    __shared__ int sIL[64], sJL[64];
    __shared__ float d3L[64][3], t3L[64][3], tbL[64];

    unsigned short* Xh = (unsigned short*)SH;
    unsigned short* Xl = (unsigned short*)(SH + 16384);
    float* preL = (float*)SH;
    float* i1bL = (float*)(SH + 16384);

    const int t = threadIdx.x;
    const int P0 = blockIdx.x * 64;
    const int isf32 = *flagp;
    const int lane = t & 63;
    const int w = t >> 6;
    const int lc = lane & 15;
    const int quad = lane >> 4;

    if (t < 64) {
        int2 ij = ((const int2*)ind2)[P0 + t];
        sIL[t] = ij.x; sJL[t] = ij.y;
    }
    for (int e = t; e < 640; e += 256) basisL[e] = ldf(basis, P0 * 10 + e, isf32);
    __syncthreads();

    // stage X = [p1[i] | p1[j]] (hi and lo) into A-frag-packed LDS
    {
        const int pr = t >> 2, s = t & 3;
        const int atom = (s < 2) ? sIL[pr] : sJL[pr];
        const int cb = (s & 1) * 32;
        const unsigned short* sh = p1h + atom * 64 + cb;
        const unsigned short* sl = p1l + atom * 64 + cb;
        const int wg = pr >> 4, m = pr & 15;
        #pragma unroll
        for (int g = 0; g < 4; g++) {
            *(uint4*)&Xh[((wg * 4 + s) * 64 + g * 16 + m) * 8] = *(const uint4*)(sh + g * 8);
            *(uint4*)&Xl[((wg * 4 + s) * 64 + g * 16 + m) * 8] = *(const uint4*)(sl + g * 8);
        }
    }
    __syncthreads();

    bf16x8 ah[4], al[4];
    #pragma unroll
    for (int s = 0; s < 4; s++) {
        ah[s] = *(const bf16x8*)&Xh[((w * 4 + s) * 64 + lane) * 8];
        al[s] = *(const bf16x8*)&Xl[((w * 4 + s) * 64 + lane) * 8];
    }

    // GEMM1: acc = Xh*Wh + Xl*Wh + Xh*Wl  (drop lo*lo)
    float sr[4][4];
    #pragma unroll
    for (int r = 0; r < 4; r++)
        #pragma unroll
        for (int ph = 0; ph < 4; ph++) sr[r][ph] = 0.f;

    for (int cc = 0; cc < 10; cc++) {
        f32x4 acc[4];
        #pragma unroll
        for (int tt = 0; tt < 4; tt++) acc[tt] = (f32x4){0.f, 0.f, 0.f, 0.f};

        __syncthreads();   // protect Bbuf from previous-iteration reads
        {
            const uint4* gsrc = (const uint4*)(piWBh + cc * 8192);
            uint4* ldst = (uint4*)Bbuf;
            #pragma unroll
            for (int r = 0; r < 4; r++) ldst[r * 256 + t] = gsrc[r * 256 + t];
        }
        __syncthreads();
        #pragma unroll
        for (int tt = 0; tt < 4; tt++) {
            #pragma unroll
            for (int s = 0; s < 4; s++) {
                bf16x8 bfr = *(const bf16x8*)&Bbuf[((tt * 4 + s) * 64 + lane) * 8];
                acc[tt] = __builtin_amdgcn_mfma_f32_16x16x32_bf16(ah[s], bfr, acc[tt], 0, 0, 0);
                acc[tt] = __builtin_amdgcn_mfma_f32_16x16x32_bf16(al[s], bfr, acc[tt], 0, 0, 0);
            }
        }
        __syncthreads();   // all reads of Wh chunk done
        {
            const uint4* gsrc = (const uint4*)(piWBl + cc * 8192);
            uint4* ldst = (uint4*)Bbuf;
            #pragma unroll
            for (int r = 0; r < 4; r++) ldst[r * 256 + t] = gsrc[r * 256 + t];
        }
        __syncthreads();
        #pragma unroll
        for (int tt = 0; tt < 4; tt++) {
            #pragma unroll
            for (int s = 0; s < 4; s++) {
                bf16x8 bfr = *(const bf16x8*)&Bbuf[((tt * 4 + s) * 64 + lane) * 8];
                acc[tt] = __builtin_amdgcn_mfma_f32_16x16x32_bf16(ah[s], bfr, acc[tt], 0, 0, 0);
            }
            const int c = tt * 16 + lc;
            const float bias = wbuf[W_PIB + c * 10 + cc];
            #pragma unroll
            for (int r = 0; r < 4; r++) {
                const int m = w * 16 + quad * 4 + r;
                const float h = tanhf(acc[tt][r] + bias);
                sr[r][tt] += h * basisL[m * 10 + cc];
            }
        }
    }

    // write pre into preL (overlays dead X staging; barriers since afr loads passed)
    #pragma unroll
    for (int r = 0; r < 4; r++)
        #pragma unroll
        for (int ph = 0; ph < 4; ph++)
            preL[(w * 16 + quad * 4 + r) * 68 + ph * 16 + lc] = sr[r][ph];
    __syncthreads();

    // GEMM2 A-split: pre -> hi/lo bf16 fragments
    bf16x8 ah2[2], al2[2];
    {
        const int row = w * 16 + lc;
        #pragma unroll
        for (int s2 = 0; s2 < 2; s2++) {
            const float* pr2 = &preL[row * 68 + s2 * 32 + quad * 8];
            #pragma unroll
            for (int j = 0; j < 8; j++) {
                const float x = pr2[j];
                const short hs = f2bs(x);
                ah2[s2][j] = hs;
                al2[s2][j] = f2bs(x - bs2f(hs));
            }
        }
    }
    __syncthreads();   // all preL reads done before i1bL overlay writes

    #pragma unroll
    for (int ct = 0; ct < 8; ct++) {
        f32x4 acc = {0.f, 0.f, 0.f, 0.f};
        #pragma unroll
        for (int s2 = 0; s2 < 2; s2++) {
            bf16x8 bh = *(const bf16x8*)&iiWh[((ct * 2 + s2) * 64 + lane) * 8];
            bf16x8 bl = *(const bf16x8*)&iiWl[((ct * 2 + s2) * 64 + lane) * 8];
            acc = __builtin_amdgcn_mfma_f32_16x16x32_bf16(ah2[s2], bh, acc, 0, 0, 0);
            acc = __builtin_amdgcn_mfma_f32_16x16x32_bf16(al2[s2], bh, acc, 0, 0, 0);
            acc = __builtin_amdgcn_mfma_f32_16x16x32_bf16(ah2[s2], bl, acc, 0, 0, 0);
        }
        const int ch = ct * 16 + lc;
        if (FULLMODE) {
            #pragma unroll
            for (int r = 0; r < 4; r++) {
                const int m = w * 16 + quad * 4 + r;
                outA[(size_t)(P0 + m) * 128 + ch] = tanhf(acc[r]);
            }
        } else {
            #pragma unroll
            for (int r = 0; r < 4; r++) {
                const int m = w * 16 + quad * 4 + r;
                const float val = tanhf(acc[r]);
                atomicAdd(&outA[(size_t)sIL[m] * 128 + ch], val);
                if (ch >= 64) i1bL[m * 64 + (ch - 64)] = val;
            }
        }
    }

    if (!FULLMODE) {
        __syncthreads();
        if (t < 64) {   // geometry for pair t
            const int m = t;
            const int ia = sIL[m];
            const float vi0 = vglob[ia * 3 + 0], vi1 = vglob[ia * 3 + 1], vi2 = vglob[ia * 3 + 2];
            const float d0 = ldf(d3, (P0 + m) * 3 + 0, isf32);
            const float d1 = ldf(d3, (P0 + m) * 3 + 1, isf32);
            const float d2 = ldf(d3, (P0 + m) * 3 + 2, isf32);
            d3L[m][0] = d0; d3L[m][1] = d1; d3L[m][2] = d2;
            const float proj = vi0 * d0 + vi1 * d1 + vi2 * d2;
            const float w0 = vi0 - proj * d0, w1 = vi1 - proj * d1, w2v = vi2 - proj * d2;
            const float w2 = w0 * w0 + w1 * w1 + w2v * w2v;
            const float g = w2 / (w2 + 1e-4f);
            const float rs = rsqrtf(w2 + 1e-6f);
            t3L[m][0] = w0 * rs * g; t3L[m][1] = w1 * rs * g; t3L[m][2] = w2v * rs * g;
            const float f = ldf(fc, P0 + m, isf32);
            tbL[m] = g * f * f;
        }
        __syncthreads();
        const int c = lane;
        #pragma unroll 4
        for (int mm = 0; mm < 16; mm++) {
            const int m = w * 16 + mm;
            const float bv = i1bL[m * 64 + c];
            const float coef = bv * tbL[m];
            #pragma unroll
            for (int x = 0; x < 3; x++) {
                const float p3v = ldf(p3, sJL[m] * 192 + x * 64 + c, isf32);
                atomicAdd(&outB[(size_t)sIL[m] * 192 + x * 64 + c],
                          p3v * bv + d3L[m][x] * bv + t3L[m][x] * coef);
            }
        }
    }
}

// ---------------- per-atom gather-reducer + fused epilogue (full path) ----------------
__global__ __launch_bounds__(64) void k_reduce(
    const int* __restrict__ ind2, const void* __restrict__ d3,
    const void* __restrict__ fc, const void* __restrict__ p3,
    const float* __restrict__ ip, const int* __restrict__ perm,
    const int* __restrict__ offs, const float* __restrict__ wbuf,
    const int* __restrict__ flagp, void* __restrict__ out)
{
    const int a = blockIdx.x;
    const int l = threadIdx.x;
    const int isf32 = *flagp;
    const int q0 = offs[a], q1 = offs[a + 1];

    float vx = 0.f, vy = 0.f, vz = 0.f;
    for (int q = q0 + l; q < q1; q += 64) {
        const int p = perm[q];
        const float f = ldf(fc, p, isf32);
        vx += ldf(d3, 3 * p + 0, isf32) * f;
        vy += ldf(d3, 3 * p + 1, isf32) * f;
        vz += ldf(d3, 3 * p + 2, isf32) * f;
    }
    #pragma unroll
    for (int off = 32; off; off >>= 1) {
        vx += __shfl_xor(vx, off);
        vy += __shfl_xor(vy, off);
        vz += __shfl_xor(vz, off);
    }

    float accA = 0.f, accB = 0.f, a30 = 0.f, a31 = 0.f, a32 = 0.f;
    #pragma unroll 2
    for (int q = q0; q < q1; q++) {
        const int p = perm[q];
        const float f = ldf(fc, p, isf32);
        const float d0 = ldf(d3, 3 * p + 0, isf32);
        const float d1 = ldf(d3, 3 * p + 1, isf32);
        const float d2 = ldf(d3, 3 * p + 2, isf32);
        const float proj = vx * d0 + vy * d1 + vz * d2;
        const float w0 = vx - proj * d0, w1 = vy - proj * d1, w2v = vz - proj * d2;
        const float w2 = w0 * w0 + w1 * w1 + w2v * w2v;
        const float g = w2 / (w2 + 1e-4f);
        const float rs = rsqrtf(w2 + 1e-6f);
        const float t30 = w0 * rs * g, t31 = w1 * rs * g, t32 = w2v * rs * g;
        const float tb = g * f * f;
        const int jj = ind2[2 * p + 1];
        const float ipa = ip[p * 128 + l];
        const float ipb = ip[p * 128 + 64 + l];
        accA += ipa; accB += ipb;
        const float coef = ipb * tb;
        a30 += ldf(p3, jj * 192 + l, isf32) * ipb + d0 * ipb + t30 * coef;
        a31 += ldf(p3, jj * 192 + 64 + l, isf32) * ipb + d1 * ipb + t31 * coef;
        a32 += ldf(p3, jj * 192 + 128 + l, isf32) * ipb + d2 * ipb + t32 * coef;
    }

    __shared__ float s1m[128];
    __shared__ float p3s[192];
    __shared__ float hA[64];
    __shared__ float cat[128];
    __shared__ float hB[64];
    s1m[l] = accA; s1m[64 + l] = accB;
    p3s[l] = a30; p3s[64 + l] = a31; p3s[128 + l] = a32;
    __syncthreads();

    const float* ppW1 = wbuf + W_PPOSTW1;
    const float* ppW2 = wbuf + W_PPOSTW2;
    const float* eqW  = wbuf + W_EQW;
    const float* q1W  = wbuf + W_Q1W;
    const float* q1b  = wbuf + W_Q1B;
    const float* q2W  = wbuf + W_Q2W;
    const float* q2b  = wbuf + W_Q2B;

    float acc = 0.f;
    for (int k = 0; k < 128; k++) acc += s1m[k] * ppW1[k * 64 + l];
    hA[l] = tanhf(acc);
    __syncthreads();
    acc = 0.f;
    for (int k = 0; k < 64; k++) acc += hA[k] * ppW2[k * 64 + l];
    const float p1n = tanhf(acc);

    float pn0 = 0.f, pn1 = 0.f, pn2 = 0.f;
    for (int k = 0; k < 64; k++) {
        const float e = eqW[k * 64 + l];
        pn0 += p3s[k] * e;
        pn1 += p3s[64 + k] * e;
        pn2 += p3s[128 + k] * e;
    }
    cat[l] = p1n;
    cat[64 + l] = pn0 * pn0 + pn1 * pn1 + pn2 * pn2;
    __syncthreads();

    acc = q1b[l];
    for (int k = 0; k < 128; k++) acc += cat[k] * q1W[k * 64 + l];
    hB[l] = tanhf(acc);
    __syncthreads();

    float g1 = q2b[l], g3 = q2b[64 + l];
    for (int k = 0; k < 64; k++) {
        const float hv = hB[k];
        g1 += hv * q2W[k * 128 + l];
        g3 += hv * q2W[k * 128 + 64 + l];
    }
    g1 = tanhf(g1);
    g3 = tanhf(g3);

    if (isf32) {
        float* p1o = (float*)out;
        float* p3o = p1o + 640000;
        p1o[a * 64 + l] = g1;
        p3o[a * 192 + l] = pn0 * g3;
        p3o[a * 192 + 64 + l] = pn1 * g3;
        p3o[a * 192 + 128 + l] = pn2 * g3;
    } else {
        __hip_bfloat16* p1o = (__hip_bfloat16*)out;
        __hip_bfloat16* p3o = p1o + 640000;
        p1o[a * 64 + l] = __float2bfloat16(g1);
        p3o[a * 192 + l] = __float2bfloat16(pn0 * g3);
        p3o[a * 192 + 64 + l] = __float2bfloat16(pn1 * g3);
        p3o[a * 192 + 128 + l] = __float2bfloat16(pn2 * g3);
    }
}

// ---------------- per-atom epilogue (atomic path) ----------------
__global__ __launch_bounds__(256) void k_final(
    const float* __restrict__ p1scat, const float* __restrict__ p3acc,
    const float* __restrict__ wbuf, const int* __restrict__ flagp,
    void* __restrict__ out)
{
    const float* ppW1 = wbuf + W_PPOSTW1;
    const float* ppW2 = wbuf + W_PPOSTW2;
    const float* eqW  = wbuf + W_EQW;
    const float* q1W  = wbuf + W_Q1W;
    const float* q1b  = wbuf + W_Q1B;
    const float* q2W  = wbuf + W_Q2W;
    const float* q2b  = wbuf + W_Q2B;
    const int isf32 = *flagp;

    __shared__ float s1[4][128];
    __shared__ float hA[4][64];
    __shared__ float cat[4][128];
    __shared__ float p3a[4][192];
    const int t = threadIdx.x;
    const int slot = t >> 6, c = t & 63;
    const int atom = blockIdx.x * 4 + slot;

    s1[slot][c]        = p1scat[atom * 128 + c];
    s1[slot][64 + c]   = p1scat[atom * 128 + 64 + c];
    p3a[slot][c]       = p3acc[atom * 192 + c];
    p3a[slot][64 + c]  = p3acc[atom * 192 + 64 + c];
    p3a[slot][128 + c] = p3acc[atom * 192 + 128 + c];
    __syncthreads();

    float acc = 0.f;
    for (int k = 0; k < 128; k++) acc += s1[slot][k] * ppW1[k * 64 + c];
    hA[slot][c] = tanhf(acc);
    __syncthreads();
    acc = 0.f;
    for (int k = 0; k < 64; k++) acc += hA[slot][k] * ppW2[k * 64 + c];
    cat[slot][c] = tanhf(acc);

    float pn[3];
    float dot = 0.f;
    #pragma unroll
    for (int x = 0; x < 3; x++) {
        float a = 0.f;
        for (int k = 0; k < 64; k++) a += p3a[slot][x * 64 + k] * eqW[k * 64 + c];
        pn[x] = a;
        dot += a * a;
    }
    cat[slot][64 + c] = dot;
    __syncthreads();

    acc = q1b[c];
    for (int k = 0; k < 128; k++) acc += cat[slot][k] * q1W[k * 64 + c];
    __syncthreads();
    hA[slot][c] = tanhf(acc);
    __syncthreads();

    float g1acc = q2b[c], g3acc = q2b[c + 64];
    for (int k = 0; k < 64; k++) {
        const float hv = hA[slot][k];
        g1acc += hv * q2W[k * 128 + c];
        g3acc += hv * q2W[k * 128 + c + 64];
    }
    const float g1 = tanhf(g1acc);
    const float g3 = tanhf(g3acc);
    if (isf32) {
        float* p1o = (float*)out;
        float* p3o = p1o + 640000;
        p1o[atom * 64 + c] = g1;
        #pragma unroll
        for (int x = 0; x < 3; x++) p3o[atom * 192 + x * 64 + c] = pn[x] * g3;
    } else {
        __hip_bfloat16* p1o = (__hip_bfloat16*)out;
        __hip_bfloat16* p3o = p1o + 640000;
        p1o[atom * 64 + c] = __float2bfloat16(g1);
        #pragma unroll
        for (int x = 0; x < 3; x++) p3o[atom * 192 + x * 64 + c] = __float2bfloat16(pn[x] * g3);
    }
}

extern "C" void kernel_launch(void* const* d_in, const int* in_sizes, int n_in,
                              void* d_out, int out_size, void* d_ws, size_t ws_size,
                              hipStream_t stream)
{
    const int* ind2 = (const int*)d_in[0];
    const void* p1    = d_in[1];
    const void* p3    = d_in[2];
    const void* basis = d_in[3];
    const void* d3    = d_in[4];
    const void* fc    = d_in[5];

    char* W = (char*)d_ws;
    float* wbuf  = (float*)(W + 0);                       // 528128 B
    short* piWBh = (short*)(W + 528128);                  // 163840 B
    short* piWBl = (short*)(W + 691968);                  // 163840 B
    short* iiWh  = (short*)(W + 855808);                  // 16384 B
    short* iiWl  = (short*)(W + 872192);                  // 16384 B
    unsigned short* p1h = (unsigned short*)(W + 888576);  // 1280000 B
    unsigned short* p1l = (unsigned short*)(W + 2168576); // 1280000 B
    int* flag = (int*)(W + 3448576);                      // 4 B; region ends 3448640

    const int full = (ws_size >= 168688704ULL) ? 1 : 0;

    k_probe<<<1, 64, 0, stream>>>(d3, flag);
    k_convert<<<516, 256, 0, stream>>>(
        d_in[6], d_in[7], d_in[8], d_in[9], d_in[10], d_in[11], d_in[12],
        d_in[13], d_in[14], d_in[15], d_in[16], d_in[17], d_in[18], d_in[19],
        wbuf, flag);
    k_pack<<<352, 256, 0, stream>>>(wbuf, piWBh, piWBl, iiWh, iiWl);
    k_p1in<<<2500, 256, 0, stream>>>(p1, wbuf, flag, p1h, p1l);

    if (full) {
        int* cnt  = (int*)(W + 3448640);       // 40000 B
        int* offs = (int*)(W + 3488640);       // 40016 B
        int* cur  = (int*)(W + 3528704);       // 40000 B
        int* perm = (int*)(W + 3568704);       // 1280000 B
        float* ip = (float*)(W + 4848704);     // 163840000 B -> ends 168688704

        hipMemsetAsync(cnt, 0, 40000, stream);
        k_hist<<<1250, 256, 0, stream>>>(ind2, cnt);
        k_scan<<<1, 256, 0, stream>>>(cnt, offs);
        k_cpcur<<<40, 256, 0, stream>>>(offs, cur);
        k_scatter<<<1250, 256, 0, stream>>>(ind2, cur, perm);
        k_pairs_t<1><<<5000, 256, 0, stream>>>(ind2, basis, d3, fc, p3,
                                               wbuf, piWBh, piWBl, iiWh, iiWl,
                                               p1h, p1l, flag, nullptr, ip, nullptr);
        k_reduce<<<10000, 64, 0, stream>>>(ind2, d3, fc, p3, ip, perm, offs,
                                           wbuf, flag, d_out);
    } else {
        float* v      = (float*)(W + 3448640); // 120000 B
        float* p1scat = (float*)(W + 3568640); // 5120000 B
        float* p3acc  = (float*)(W + 8688640); // 7680000 B -> ends 16368640

        hipMemsetAsync(v, 0, 120000 + 5120000 + 7680000, stream);
        k_vscat<<<1250, 256, 0, stream>>>(ind2, d3, fc, flag, v);
        k_pairs_t<0><<<5000, 256, 0, stream>>>(ind2, basis, d3, fc, p3,
                                               wbuf, piWBh, piWBl, iiWh, iiWl,
                                               p1h, p1l, flag, v, p1scat, p3acc);
        k_final<<<2500, 256, 0, stream>>>(p1scat, p3acc, wbuf, flag, d_out);
    }
}

// Round 7
// 528.283 us; speedup vs baseline: 5.6157x; 1.3021x over previous
//
#include <hip/hip_runtime.h>
#include <hip/hip_bf16.h>

#define N_ATOMS 10000
#define N_PAIRS 320000
#define C_ 64
#define NB_ 10

typedef short bf16x8 __attribute__((ext_vector_type(8)));
typedef float f32x4 __attribute__((ext_vector_type(4)));

__device__ __forceinline__ float bf2f(__hip_bfloat16 x) { return __bfloat162float(x); }
__device__ __forceinline__ float ldf(const void* p, int i, int isf32) {
    return isf32 ? ((const float*)p)[i] : bf2f(((const __hip_bfloat16*)p)[i]);
}
__device__ __forceinline__ short f2bs(float x) {
    __hip_bfloat16 h = __float2bfloat16(x);
    return *reinterpret_cast<short*>(&h);
}
__device__ __forceinline__ float bs2f(unsigned short s) {
    return __uint_as_float(((unsigned)s) << 16);
}
// fast tanh: 1 - 2/(exp(2x)+1). err ~1e-6, saturates correctly at +-inf.
__device__ __forceinline__ float tanh_fast(float x) {
    const float e = __expf(2.0f * x);
    return 1.0f - 2.0f * __builtin_amdgcn_rcpf(e + 1.0f);
}

// wbuf f32 offsets
#define W_PPREW1 0
#define W_PPREB1 4096
#define W_PPREW2 4160
#define W_PPREB2 8256
#define W_PIW    8320
#define W_PIB    90240
#define W_IIW    90880
#define W_PPOSTW1 99072
#define W_PPOSTW2 107264
#define W_EQW    111360
#define W_Q1W    115456
#define W_Q1B    123648
#define W_Q2W    123712
#define W_Q2B    131904
#define W_TOTAL  132032

// ---------------- probe dtype ----------------
__global__ void k_probe(const void* __restrict__ d3, int* __restrict__ flag)
{
    if (threadIdx.x == 0 && blockIdx.x == 0) {
        float sf = 0.f, sb = 0.f;
        const float* f = (const float*)d3;
        const __hip_bfloat16* b = (const __hip_bfloat16*)d3;
        for (int r = 0; r < 4; r++) {
            float x = f[r*3], y = f[r*3+1], z = f[r*3+2];
            float n = x*x + y*y + z*z;
            sf += isfinite(n) ? fabsf(n - 1.f) : 1e30f;
            float xb = bf2f(b[r*3]), yb = bf2f(b[r*3+1]), zb = bf2f(b[r*3+2]);
            float nb = xb*xb + yb*yb + zb*zb;
            sb += isfinite(nb) ? fabsf(nb - 1.f) : 1e30f;
        }
        *flag = (sf < sb) ? 1 : 0;
    }
}

// ---------------- gather all weights into f32 wbuf ----------------
__global__ __launch_bounds__(256) void k_convert(
    const void* s0, const void* s1, const void* s2, const void* s3,
    const void* s4, const void* s5, const void* s6, const void* s7,
    const void* s8, const void* s9, const void* s10, const void* s11,
    const void* s12, const void* s13,
    float* __restrict__ wbuf, const int* __restrict__ flagp)
{
    const int idx = blockIdx.x * 256 + threadIdx.x;
    if (idx >= W_TOTAL) return;
    const int isf32 = *flagp;
    const int offs[15] = {W_PPREW1, W_PPREB1, W_PPREW2, W_PPREB2, W_PIW, W_PIB,
                          W_IIW, W_PPOSTW1, W_PPOSTW2, W_EQW, W_Q1W, W_Q1B,
                          W_Q2W, W_Q2B, W_TOTAL};
    const void* srcs[14] = {s0,s1,s2,s3,s4,s5,s6,s7,s8,s9,s10,s11,s12,s13};
    int t = 0;
    while (idx >= offs[t + 1]) t++;
    wbuf[idx] = ldf(srcs[t], idx - offs[t], isf32);
}

// ---------------- pack MFMA B-operand buffers (hi + lo split) ----------------
__global__ __launch_bounds__(256) void k_pack(
    const float* __restrict__ wbuf,
    short* __restrict__ piWBh, short* __restrict__ piWBl,
    short* __restrict__ iiWh, short* __restrict__ iiWl)
{
    int idx = blockIdx.x * 256 + threadIdx.x;
    if (idx < 81920) {
        const int j = idx & 7, lane = (idx >> 3) & 63, s = (idx >> 9) & 3, T = idx >> 11;
        const int k = s * 32 + (lane >> 4) * 8 + j;
        const int colp = T * 16 + (lane & 15);
        const int b = colp >> 6, c = colp & 63;
        const float v = wbuf[W_PIW + k * 640 + c * 10 + b];
        const short hs = f2bs(v);
        piWBh[idx] = hs;
        piWBl[idx] = f2bs(v - bs2f((unsigned short)hs));
        return;
    }
    idx -= 81920;
    if (idx < 8192) {
        const int j = idx & 7, lane = (idx >> 3) & 63, s2 = (idx >> 9) & 1, ct = idx >> 10;
        const int k = s2 * 32 + (lane >> 4) * 8 + j;
        const int col = ct * 16 + (lane & 15);
        const float wv = wbuf[W_IIW + k * 128 + col];
        const short hs = f2bs(wv);
        iiWh[idx] = hs;
        iiWl[idx] = f2bs(wv - bs2f((unsigned short)hs));
    }
}

// ---------------- p1_in split into hi/lo bf16 ----------------
__global__ __launch_bounds__(256) void k_p1in(
    const void* __restrict__ p1, const float* __restrict__ wbuf,
    const int* __restrict__ flagp,
    unsigned short* __restrict__ p1h, unsigned short* __restrict__ p1l)
{
    const float* W1 = wbuf + W_PPREW1;
    const float* b1 = wbuf + W_PPREB1;
    const float* W2 = wbuf + W_PPREW2;
    const float* b2 = wbuf + W_PPREB2;
    const int isf32 = *flagp;
    __shared__ float x[4][C_];
    __shared__ float h[4][C_];
    const int t = threadIdx.x;
    const int slot = t >> 6, c = t & 63;
    const int atom = blockIdx.x * 4 + slot;
    x[slot][c] = ldf(p1, atom * C_ + c, isf32);
    __syncthreads();
    float acc = b1[c];
    for (int k = 0; k < C_; k++) acc += x[slot][k] * W1[k * C_ + c];
    h[slot][c] = tanh_fast(acc);
    __syncthreads();
    acc = b2[c];
    for (int k = 0; k < C_; k++) acc += h[slot][k] * W2[k * C_ + c];
    const float f = tanh_fast(acc);
    const short hs = f2bs(f);
    p1h[atom * C_ + c] = (unsigned short)hs;
    p1l[atom * C_ + c] = (unsigned short)f2bs(f - bs2f((unsigned short)hs));
}

// ---------------- sort machinery (full path) ----------------
__global__ __launch_bounds__(256) void k_hist(const int* __restrict__ ind2, int* __restrict__ cnt)
{
    const int p = blockIdx.x * 256 + threadIdx.x;
    if (p < N_PAIRS) atomicAdd(&cnt[ind2[2 * p]], 1);
}
__global__ __launch_bounds__(256) void k_scan(const int* __restrict__ cnt, int* __restrict__ offs)
{
    __shared__ int part[256];
    __shared__ int base[257];
    const int t = threadIdx.x;
    const int lo = t * 40, hi = (lo + 40 < N_ATOMS) ? lo + 40 : N_ATOMS;
    int s = 0;
    for (int b = lo; b < hi; b++) s += cnt[b];
    part[t] = s;
    __syncthreads();
    if (t == 0) {
        int run = 0;
        for (int i = 0; i < 256; i++) { base[i] = run; run += part[i]; }
        base[256] = run;
    }
    __syncthreads();
    int run = base[t];
    for (int b = lo; b < hi; b++) { offs[b] = run; run += cnt[b]; }
    if (t == 0) offs[N_ATOMS] = base[256];
}
__global__ __launch_bounds__(256) void k_cpcur(const int* __restrict__ offs, int* __restrict__ cur)
{
    const int i = blockIdx.x * 256 + threadIdx.x;
    if (i < N_ATOMS) cur[i] = offs[i];
}
__global__ __launch_bounds__(256) void k_scatter(const int* __restrict__ ind2,
                                                 int* __restrict__ cur, int* __restrict__ perm)
{
    const int p = blockIdx.x * 256 + threadIdx.x;
    if (p >= N_PAIRS) return;
    const int pos = atomicAdd(&cur[ind2[2 * p]], 1);
    perm[pos] = p;
}

// ---------------- v scatter (atomic path only) ----------------
__global__ __launch_bounds__(256) void k_vscat(
    const int* __restrict__ ind2, const void* __restrict__ d3,
    const void* __restrict__ fc, const int* __restrict__ flagp, float* __restrict__ v)
{
    const int p = blockIdx.x * 256 + threadIdx.x;
    if (p >= N_PAIRS) return;
    const int isf32 = *flagp;
    const int ia = ind2[2 * p];
    const float f = ldf(fc, p, isf32);
    atomicAdd(&v[ia * 3 + 0], ldf(d3, p * 3 + 0, isf32) * f);
    atomicAdd(&v[ia * 3 + 1], ldf(d3, p * 3 + 1, isf32) * f);
    atomicAdd(&v[ia * 3 + 2], ldf(d3, p * 3 + 2, isf32) * f);
}

// ---------------- main per-pair MFMA kernel ----------------
// A fragments loaded directly from global (p1h/p1l L2-resident, 16B/lane).
// FULLMODE=1: ip stored as f32 (bf16 was a 1.0-absmax regression: the
// t3*i1b^2*tb term accumulates coherently per atom, amplifying the 2^-9
// quantization to ~454*0.2% ~= 1.0 on p3_out. Keep f32.)
template<int FULLMODE>
__global__ __launch_bounds__(256) void k_pairs_t(
    const int* __restrict__ ind2, const void* __restrict__ basis,
    const void* __restrict__ d3, const void* __restrict__ fc,
    const void* __restrict__ p3,
    const float* __restrict__ wbuf,
    const short* __restrict__ piWBh, const short* __restrict__ piWBl,
    const short* __restrict__ iiWh, const short* __restrict__ iiWl,
    const unsigned short* __restrict__ p1h, const unsigned short* __restrict__ p1l,
    const int* __restrict__ flagp, const float* __restrict__ vglob,
    float* __restrict__ outA, float* __restrict__ outB)
{
    __shared__ __align__(16) unsigned short Bbuf[8192];   // 16 KB B-chunk
    __shared__ __align__(16) char SH[17408];              // preL / i1bL overlay
    __shared__ float basisL[640];
    __shared__ int sIL[64], sJL[64];
    __shared__ float d3L[64][3], t3L[64][3], tbL[64];

    float* preL = (float*)SH;
    float* i1bL = (float*)SH;

    const int t = threadIdx.x;
    const int P0 = blockIdx.x * 64;
    const int isf32 = *flagp;
    const int lane = t & 63;
    const int w = t >> 6;
    const int lc = lane & 15;
    const int quad = lane >> 4;

    if (t < 64) {
        int2 ij = ((const int2*)ind2)[P0 + t];
        sIL[t] = ij.x; sJL[t] = ij.y;
    }
    for (int e = t; e < 640; e += 256) basisL[e] = ldf(basis, P0 * 10 + e, isf32);
    __syncthreads();

    // A-frags: row m = lc (pair w*16+lc), k = s*32 + quad*8 + j
    bf16x8 ah[4], al[4];
    {
        const int ia = sIL[w * 16 + lc];
        const int ja = sJL[w * 16 + lc];
        #pragma unroll
        for (int s = 0; s < 4; s++) {
            const int atom = (s < 2) ? ia : ja;
            const int off = atom * 64 + (s & 1) * 32 + quad * 8;
            ah[s] = *(const bf16x8*)(p1h + off);
            al[s] = *(const bf16x8*)(p1l + off);
        }
    }

    // GEMM1: acc = Xh*Wh + Xl*Wh + Xh*Wl  (drop lo*lo)
    float sr[4][4];
    #pragma unroll
    for (int r = 0; r < 4; r++)
        #pragma unroll
        for (int ph = 0; ph < 4; ph++) sr[r][ph] = 0.f;

    for (int cc = 0; cc < 10; cc++) {
        f32x4 acc[4];
        #pragma unroll
        for (int tt = 0; tt < 4; tt++) acc[tt] = (f32x4){0.f, 0.f, 0.f, 0.f};

        __syncthreads();
        {
            const uint4* gsrc = (const uint4*)(piWBh + cc * 8192);
            uint4* ldst = (uint4*)Bbuf;
            #pragma unroll
            for (int r = 0; r < 4; r++) ldst[r * 256 + t] = gsrc[r * 256 + t];
        }
        __syncthreads();
        #pragma unroll
        for (int tt = 0; tt < 4; tt++) {
            #pragma unroll
            for (int s = 0; s < 4; s++) {
                bf16x8 bfr = *(const bf16x8*)&Bbuf[((tt * 4 + s) * 64 + lane) * 8];
                acc[tt] = __builtin_amdgcn_mfma_f32_16x16x32_bf16(ah[s], bfr, acc[tt], 0, 0, 0);
                acc[tt] = __builtin_amdgcn_mfma_f32_16x16x32_bf16(al[s], bfr, acc[tt], 0, 0, 0);
            }
        }
        __syncthreads();
        {
            const uint4* gsrc = (const uint4*)(piWBl + cc * 8192);
            uint4* ldst = (uint4*)Bbuf;
            #pragma unroll
            for (int r = 0; r < 4; r++) ldst[r * 256 + t] = gsrc[r * 256 + t];
        }
        __syncthreads();
        #pragma unroll
        for (int tt = 0; tt < 4; tt++) {
            #pragma unroll
            for (int s = 0; s < 4; s++) {
                bf16x8 bfr = *(const bf16x8*)&Bbuf[((tt * 4 + s) * 64 + lane) * 8];
                acc[tt] = __builtin_amdgcn_mfma_f32_16x16x32_bf16(ah[s], bfr, acc[tt], 0, 0, 0);
            }
            const int c = tt * 16 + lc;
            const float bias = wbuf[W_PIB + c * 10 + cc];
            #pragma unroll
            for (int r = 0; r < 4; r++) {
                const int m = w * 16 + quad * 4 + r;
                const float h = tanh_fast(acc[tt][r] + bias);
                sr[r][tt] += h * basisL[m * 10 + cc];
            }
        }
    }

    // pre -> LDS (C-layout to A-layout transform)
    #pragma unroll
    for (int r = 0; r < 4; r++)
        #pragma unroll
        for (int ph = 0; ph < 4; ph++)
            preL[(w * 16 + quad * 4 + r) * 68 + ph * 16 + lc] = sr[r][ph];
    __syncthreads();

    bf16x8 ah2[2], al2[2];
    {
        const int row = w * 16 + lc;
        #pragma unroll
        for (int s2 = 0; s2 < 2; s2++) {
            const float* pr2 = &preL[row * 68 + s2 * 32 + quad * 8];
            #pragma unroll
            for (int j = 0; j < 8; j++) {
                const float x = pr2[j];
                const short hs = f2bs(x);
                ah2[s2][j] = hs;
                al2[s2][j] = f2bs(x - bs2f((unsigned short)hs));
            }
        }
    }
    __syncthreads();   // preL reads done before i1bL overlay writes

    #pragma unroll
    for (int ct = 0; ct < 8; ct++) {
        f32x4 acc = {0.f, 0.f, 0.f, 0.f};
        #pragma unroll
        for (int s2 = 0; s2 < 2; s2++) {
            bf16x8 bh = *(const bf16x8*)&iiWh[((ct * 2 + s2) * 64 + lane) * 8];
            bf16x8 bl = *(const bf16x8*)&iiWl[((ct * 2 + s2) * 64 + lane) * 8];
            acc = __builtin_amdgcn_mfma_f32_16x16x32_bf16(ah2[s2], bh, acc, 0, 0, 0);
            acc = __builtin_amdgcn_mfma_f32_16x16x32_bf16(al2[s2], bh, acc, 0, 0, 0);
            acc = __builtin_amdgcn_mfma_f32_16x16x32_bf16(ah2[s2], bl, acc, 0, 0, 0);
        }
        const int ch = ct * 16 + lc;
        if (FULLMODE) {
            #pragma unroll
            for (int r = 0; r < 4; r++) {
                const int m = w * 16 + quad * 4 + r;
                outA[(size_t)(P0 + m) * 128 + ch] = tanh_fast(acc[r]);
            }
        } else {
            #pragma unroll
            for (int r = 0; r < 4; r++) {
                const int m = w * 16 + quad * 4 + r;
                const float val = tanh_fast(acc[r]);
                atomicAdd(&outA[(size_t)sIL[m] * 128 + ch], val);
                if (ch >= 64) i1bL[m * 64 + (ch - 64)] = val;
            }
        }
    }

    if (!FULLMODE) {
        __syncthreads();
        if (t < 64) {
            const int m = t;
            const int ia = sIL[m];
            const float vi0 = vglob[ia * 3 + 0], vi1 = vglob[ia * 3 + 1], vi2 = vglob[ia * 3 + 2];
            const float d0 = ldf(d3, (P0 + m) * 3 + 0, isf32);
            const float d1 = ldf(d3, (P0 + m) * 3 + 1, isf32);
            const float d2 = ldf(d3, (P0 + m) * 3 + 2, isf32);
            d3L[m][0] = d0; d3L[m][1] = d1; d3L[m][2] = d2;
            const float proj = vi0 * d0 + vi1 * d1 + vi2 * d2;
            const float w0 = vi0 - proj * d0, w1 = vi1 - proj * d1, w2v = vi2 - proj * d2;
            const float w2 = w0 * w0 + w1 * w1 + w2v * w2v;
            const float g = w2 / (w2 + 1e-4f);
            const float rs = rsqrtf(w2 + 1e-6f);
            t3L[m][0] = w0 * rs * g; t3L[m][1] = w1 * rs * g; t3L[m][2] = w2v * rs * g;
            const float f = ldf(fc, P0 + m, isf32);
            tbL[m] = g * f * f;
        }
        __syncthreads();
        const int c = lane;
        #pragma unroll 4
        for (int mm = 0; mm < 16; mm++) {
            const int m = w * 16 + mm;
            const float bv = i1bL[m * 64 + c];
            const float coef = bv * tbL[m];
            #pragma unroll
            for (int x = 0; x < 3; x++) {
                const float p3v = ldf(p3, sJL[m] * 192 + x * 64 + c, isf32);
                atomicAdd(&outB[(size_t)sIL[m] * 192 + x * 64 + c],
                          p3v * bv + d3L[m][x] * bv + t3L[m][x] * coef);
            }
        }
    }
}

// ---------------- per-atom gather-reducer + fused epilogue (full path) ----------------
__global__ __launch_bounds__(64) void k_reduce(
    const int* __restrict__ ind2, const void* __restrict__ d3,
    const void* __restrict__ fc, const void* __restrict__ p3,
    const float* __restrict__ ip, const int* __restrict__ perm,
    const int* __restrict__ offs, const float* __restrict__ wbuf,
    const int* __restrict__ flagp, void* __restrict__ out)
{
    const int a = blockIdx.x;
    const int l = threadIdx.x;
    const int isf32 = *flagp;
    const int q0 = offs[a], q1 = offs[a + 1];

    float vx = 0.f, vy = 0.f, vz = 0.f;
    for (int q = q0 + l; q < q1; q += 64) {
        const int p = perm[q];
        const float f = ldf(fc, p, isf32);
        vx += ldf(d3, 3 * p + 0, isf32) * f;
        vy += ldf(d3, 3 * p + 1, isf32) * f;
        vz += ldf(d3, 3 * p + 2, isf32) * f;
    }
    #pragma unroll
    for (int off = 32; off; off >>= 1) {
        vx += __shfl_xor(vx, off);
        vy += __shfl_xor(vy, off);
        vz += __shfl_xor(vz, off);
    }

    float accA = 0.f, accB = 0.f, a30 = 0.f, a31 = 0.f, a32 = 0.f;
    #pragma unroll 2
    for (int q = q0; q < q1; q++) {
        const int p = perm[q];
        const float f = ldf(fc, p, isf32);
        const float d0 = ldf(d3, 3 * p + 0, isf32);
        const float d1 = ldf(d3, 3 * p + 1, isf32);
        const float d2 = ldf(d3, 3 * p + 2, isf32);
        const float proj = vx * d0 + vy * d1 + vz * d2;
        const float w0 = vx - proj * d0, w1 = vy - proj * d1, w2v = vz - proj * d2;
        const float w2 = w0 * w0 + w1 * w1 + w2v * w2v;
        const float g = w2 / (w2 + 1e-4f);
        const float rs = rsqrtf(w2 + 1e-6f);
        const float t30 = w0 * rs * g, t31 = w1 * rs * g, t32 = w2v * rs * g;
        const float tb = g * f * f;
        const int jj = ind2[2 * p + 1];
        const float ipa = ip[(size_t)p * 128 + l];
        const float ipb = ip[(size_t)p * 128 + 64 + l];
        accA += ipa; accB += ipb;
        const float coef = ipb * tb;
        a30 += ldf(p3, jj * 192 + l, isf32) * ipb + d0 * ipb + t30 * coef;
        a31 += ldf(p3, jj * 192 + 64 + l, isf32) * ipb + d1 * ipb + t31 * coef;
        a32 += ldf(p3, jj * 192 + 128 + l, isf32) * ipb + d2 * ipb + t32 * coef;
    }

    __shared__ float s1m[128];
    __shared__ float p3s[192];
    __shared__ float hA[64];
    __shared__ float cat[128];
    __shared__ float hB[64];
    s1m[l] = accA; s1m[64 + l] = accB;
    p3s[l] = a30; p3s[64 + l] = a31; p3s[128 + l] = a32;
    __syncthreads();

    const float* ppW1 = wbuf + W_PPOSTW1;
    const float* ppW2 = wbuf + W_PPOSTW2;
    const float* eqW  = wbuf + W_EQW;
    const float* q1W  = wbuf + W_Q1W;
    const float* q1b  = wbuf + W_Q1B;
    const float* q2W  = wbuf + W_Q2W;
    const float* q2b  = wbuf + W_Q2B;

    float acc = 0.f;
    for (int k = 0; k < 128; k++) acc += s1m[k] * ppW1[k * 64 + l];
    hA[l] = tanh_fast(acc);
    __syncthreads();
    acc = 0.f;
    for (int k = 0; k < 64; k++) acc += hA[k] * ppW2[k * 64 + l];
    const float p1n = tanh_fast(acc);

    float pn0 = 0.f, pn1 = 0.f, pn2 = 0.f;
    for (int k = 0; k < 64; k++) {
        const float e = eqW[k * 64 + l];
        pn0 += p3s[k] * e;
        pn1 += p3s[64 + k] * e;
        pn2 += p3s[128 + k] * e;
    }
    cat[l] = p1n;
    cat[64 + l] = pn0 * pn0 + pn1 * pn1 + pn2 * pn2;
    __syncthreads();

    acc = q1b[l];
    for (int k = 0; k < 128; k++) acc += cat[k] * q1W[k * 64 + l];
    hB[l] = tanh_fast(acc);
    __syncthreads();

    float g1 = q2b[l], g3 = q2b[64 + l];
    for (int k = 0; k < 64; k++) {
        const float hv = hB[k];
        g1 += hv * q2W[k * 128 + l];
        g3 += hv * q2W[k * 128 + 64 + l];
    }
    g1 = tanh_fast(g1);
    g3 = tanh_fast(g3);

    if (isf32) {
        float* p1o = (float*)out;
        float* p3o = p1o + 640000;
        p1o[a * 64 + l] = g1;
        p3o[a * 192 + l] = pn0 * g3;
        p3o[a * 192 + 64 + l] = pn1 * g3;
        p3o[a * 192 + 128 + l] = pn2 * g3;
    } else {
        __hip_bfloat16* p1o = (__hip_bfloat16*)out;
        __hip_bfloat16* p3o = p1o + 640000;
        p1o[a * 64 + l] = __float2bfloat16(g1);
        p3o[a * 192 + l] = __float2bfloat16(pn0 * g3);
        p3o[a * 192 + 64 + l] = __float2bfloat16(pn1 * g3);
        p3o[a * 192 + 128 + l] = __float2bfloat16(pn2 * g3);
    }
}

// ---------------- per-atom epilogue (atomic path) ----------------
__global__ __launch_bounds__(256) void k_final(
    const float* __restrict__ p1scat, const float* __restrict__ p3acc,
    const float* __restrict__ wbuf, const int* __restrict__ flagp,
    void* __restrict__ out)
{
    const float* ppW1 = wbuf + W_PPOSTW1;
    const float* ppW2 = wbuf + W_PPOSTW2;
    const float* eqW  = wbuf + W_EQW;
    const float* q1W  = wbuf + W_Q1W;
    const float* q1b  = wbuf + W_Q1B;
    const float* q2W  = wbuf + W_Q2W;
    const float* q2b  = wbuf + W_Q2B;
    const int isf32 = *flagp;

    __shared__ float s1[4][128];
    __shared__ float hA[4][64];
    __shared__ float cat[4][128];
    __shared__ float p3a[4][192];
    const int t = threadIdx.x;
    const int slot = t >> 6, c = t & 63;
    const int atom = blockIdx.x * 4 + slot;

    s1[slot][c]        = p1scat[atom * 128 + c];
    s1[slot][64 + c]   = p1scat[atom * 128 + 64 + c];
    p3a[slot][c]       = p3acc[atom * 192 + c];
    p3a[slot][64 + c]  = p3acc[atom * 192 + 64 + c];
    p3a[slot][128 + c] = p3acc[atom * 192 + 128 + c];
    __syncthreads();

    float acc = 0.f;
    for (int k = 0; k < 128; k++) acc += s1[slot][k] * ppW1[k * 64 + c];
    hA[slot][c] = tanh_fast(acc);
    __syncthreads();
    acc = 0.f;
    for (int k = 0; k < 64; k++) acc += hA[slot][k] * ppW2[k * 64 + c];
    cat[slot][c] = tanh_fast(acc);

    float pn[3];
    float dot = 0.f;
    #pragma unroll
    for (int x = 0; x < 3; x++) {
        float a = 0.f;
        for (int k = 0; k < 64; k++) a += p3a[slot][x * 64 + k] * eqW[k * 64 + c];
        pn[x] = a;
        dot += a * a;
    }
    cat[slot][64 + c] = dot;
    __syncthreads();

    acc = q1b[c];
    for (int k = 0; k < 128; k++) acc += cat[slot][k] * q1W[k * 64 + c];
    __syncthreads();
    hA[slot][c] = tanh_fast(acc);
    __syncthreads();

    float g1acc = q2b[c], g3acc = q2b[c + 64];
    for (int k = 0; k < 64; k++) {
        const float hv = hA[slot][k];
        g1acc += hv * q2W[k * 128 + c];
        g3acc += hv * q2W[k * 128 + c + 64];
    }
    const float g1 = tanh_fast(g1acc);
    const float g3 = tanh_fast(g3acc);
    if (isf32) {
        float* p1o = (float*)out;
        float* p3o = p1o + 640000;
        p1o[atom * 64 + c] = g1;
        #pragma unroll
        for (int x = 0; x < 3; x++) p3o[atom * 192 + x * 64 + c] = pn[x] * g3;
    } else {
        __hip_bfloat16* p1o = (__hip_bfloat16*)out;
        __hip_bfloat16* p3o = p1o + 640000;
        p1o[atom * 64 + c] = __float2bfloat16(g1);
        #pragma unroll
        for (int x = 0; x < 3; x++) p3o[atom * 192 + x * 64 + c] = __float2bfloat16(pn[x] * g3);
    }
}

extern "C" void kernel_launch(void* const* d_in, const int* in_sizes, int n_in,
                              void* d_out, int out_size, void* d_ws, size_t ws_size,
                              hipStream_t stream)
{
    const int* ind2 = (const int*)d_in[0];
    const void* p1    = d_in[1];
    const void* p3    = d_in[2];
    const void* basis = d_in[3];
    const void* d3    = d_in[4];
    const void* fc    = d_in[5];

    char* W = (char*)d_ws;
    float* wbuf  = (float*)(W + 0);                       // 528128 B
    short* piWBh = (short*)(W + 528128);                  // 163840 B
    short* piWBl = (short*)(W + 691968);                  // 163840 B
    short* iiWh  = (short*)(W + 855808);                  // 16384 B
    short* iiWl  = (short*)(W + 872192);                  // 16384 B
    unsigned short* p1h = (unsigned short*)(W + 888576);  // 1280000 B
    unsigned short* p1l = (unsigned short*)(W + 2168576); // 1280000 B
    int* flag = (int*)(W + 3448576);                      // region ends 3448640

    const int full = (ws_size >= 168688704ULL) ? 1 : 0;

    k_probe<<<1, 64, 0, stream>>>(d3, flag);
    k_convert<<<516, 256, 0, stream>>>(
        d_in[6], d_in[7], d_in[8], d_in[9], d_in[10], d_in[11], d_in[12],
        d_in[13], d_in[14], d_in[15], d_in[16], d_in[17], d_in[18], d_in[19],
        wbuf, flag);
    k_pack<<<352, 256, 0, stream>>>(wbuf, piWBh, piWBl, iiWh, iiWl);
    k_p1in<<<2500, 256, 0, stream>>>(p1, wbuf, flag, p1h, p1l);

    if (full) {
        int* cnt  = (int*)(W + 3448640);       // 40000 B
        int* offs = (int*)(W + 3488640);       // 40016 B -> pad 3528704
        int* cur  = (int*)(W + 3528704);       // 40000 B
        int* perm = (int*)(W + 3568704);       // 1280000 B
        float* ip = (float*)(W + 4848704);     // 163840000 B -> ends 168688704

        hipMemsetAsync(cnt, 0, 40000, stream);
        k_hist<<<1250, 256, 0, stream>>>(ind2, cnt);
        k_scan<<<1, 256, 0, stream>>>(cnt, offs);
        k_cpcur<<<40, 256, 0, stream>>>(offs, cur);
        k_scatter<<<1250, 256, 0, stream>>>(ind2, cur, perm);
        k_pairs_t<1><<<5000, 256, 0, stream>>>(ind2, basis, d3, fc, p3,
                                               wbuf, piWBh, piWBl, iiWh, iiWl,
                                               p1h, p1l, flag, nullptr,
                                               ip, nullptr);
        k_reduce<<<10000, 64, 0, stream>>>(ind2, d3, fc, p3, ip, perm, offs,
                                           wbuf, flag, d_out);
    } else {
        float* v      = (float*)(W + 3448640); // 120000 B
        float* p1scat = (float*)(W + 3568640); // 5120000 B
        float* p3acc  = (float*)(W + 8688640); // 7680000 B -> ends 16368640

        hipMemsetAsync(v, 0, 120000 + 5120000 + 7680000, stream);
        k_vscat<<<1250, 256, 0, stream>>>(ind2, d3, fc, flag, v);
        k_pairs_t<0><<<5000, 256, 0, stream>>>(ind2, basis, d3, fc, p3,
                                               wbuf, piWBh, piWBl, iiWh, iiWl,
                                               p1h, p1l, flag, v,
                                               p1scat, p3acc);
        k_final<<<2500, 256, 0, stream>>>(p1scat, p3acc, wbuf, flag, d_out);
    }
}